// Round 7
// baseline (154.160 us; speedup 1.0000x reference)
//
#include <hip/hip_runtime.h>
#include <math.h>

// B=32, D=2048 rank-1 self-attention, fp32.
//   k2_j = k_j*log2e ; m2_j = k2_j>=0 ? k2_j*qmax : k2_j*qmin
//   Z_j  = sum_i 2^(q_i k2_j - m2_j) ; d_j = log2(|v_j|/Z_j) - m2_j
//   out_i = sum_{j:v>0} 2^(fma(q_i,k2_j,d_j)) - sum_{j:v<0} 2^(...)
//
// R18: DIAGNOSTIC round. R17's cooperative fusion failed at launch level
// (out stayed zero; phases were verbatim R16 code) -> abandon cooperative.
// Core problem: 5 rounds of restructuring moved 141.6->134.4 while issue/
// LDS-pipe arithmetic says k3+k4 ~20-30us; budget doesn't close, and the
// hot kernels have NEVER appeared in the top-5 (all slots = ~42us harness
// fills). This round concentrates work onto fewer blocks so k3/k4 exceed
// the 42us cutoff and surface WITH counters:
//  - k3: grid 512 (4 groups/block, qs staging amortized 4x). 2 blocks/CU.
//  - k4: grid 256 (4 ic/block, kd staging amortized 4x). 1 block/CU ->
//    guaranteed visible.
// Math unchanged from R16 (passing, absmax 2.5). Readout next round:
// VALUBusy high at low occupancy -> pipe-bound, real cost is fills/gaps ->
// cut launches; VALUBusy low -> latency/LDS-serialization -> fix reads.

#define D 2048
#define BATCH 32

// workspace float offsets
#define PART_STRIDE 196608   // one splitK part: 3*65536 (m*65536 + b*D + r)
#define BQV_OFF   786432     // bucketed q values [32][2048]
#define BQI_OFF   851968     // bucketed q orig index (int) [32][2048]
#define BK2_OFF   917504     // bucketed k2 values [32][2048]
#define BKI_OFF   983040     // bucketed k2 orig index (int) [32][2048]
#define META_OFF  1048576    // per b (stride 80): [0]qmx [1]qmn [2]scale, int off[65] at +8
#define PKD_OFF   1051136    // float2[32][64][32] two-ended segs (pos up, neg down)
#define NPT_OFF   1182208    // int[32][64] npos per seg
#define SMETA_OFF 1184256    // float4[32][64]: k2min,k2max,dmax per seg

#define L2E 1.4426950408889634f

typedef short s16x8 __attribute__((ext_vector_type(8)));
typedef float f32x4 __attribute__((ext_vector_type(4)));

union FragU { s16x8 v; unsigned u[4]; };

__device__ __forceinline__ float fast_exp2(float x) {
#if __has_builtin(__builtin_amdgcn_exp2f)
  return __builtin_amdgcn_exp2f(x);
#else
  return exp2f(x);
#endif
}
__device__ __forceinline__ int bits_below(unsigned long long m) {
  return __builtin_amdgcn_mbcnt_hi((unsigned)(m >> 32),
         __builtin_amdgcn_mbcnt_lo((unsigned)m, 0));
}
__device__ __forceinline__ unsigned pack_rne(float a, float b) {
  unsigned ua = __float_as_uint(a), ub = __float_as_uint(b);
  ua = ua + 0x7FFFu + ((ua >> 16) & 1u);
  ub = ub + 0x7FFFu + ((ub >> 16) & 1u);
  return (ua >> 16) | (ub & 0xFFFF0000u);
}
__device__ __forceinline__ void pack8(const float4& fa, const float4& fb,
                                      FragU& h) {
  h.u[0] = pack_rne(fa.x, fa.y);
  h.u[1] = pack_rne(fa.z, fa.w);
  h.u[2] = pack_rne(fb.x, fb.y);
  h.u[3] = pack_rne(fb.z, fb.w);
}
__device__ __forceinline__ float sum_parts(const float* __restrict__ ws,
                                           size_t o) {
  float s0 = ws[o] + ws[o + PART_STRIDE];
  float s1 = ws[o + 2 * PART_STRIDE] + ws[o + 3 * PART_STRIDE];
  return s0 + s1;
}

// ---------------- K1: projections via LDS-free bf16 MFMA -------------------
__global__ __launch_bounds__(256, 2) void k1_proj(
    const float* __restrict__ x, const float* __restrict__ Wq,
    const float* __restrict__ Wk, const float* __restrict__ Wv,
    float* __restrict__ ws) {
  __shared__ float red[4][512];
  const int tid = threadIdx.x;
  const int lane = tid & 63, wv = tid >> 6;
  const int tile = blockIdx.x >> 2, kq = blockIdx.x & 3;
  const int m = tile >> 7, lr = (tile & 127) * 16;
  const float* W = (m == 0) ? Wq : (m == 1) ? Wk : Wv;

  const int kbase = kq * 512 + wv * 128 + (lane >> 4) * 8;
  const float* ap = W + (size_t)(lr + (lane & 15)) * D + kbase;
  const float* xp0 = x + (size_t)(lane & 15) * D + kbase;
  const float* xp1 = xp0 + 16 * D;

  float4 fa[4], fb[4], x0a[4], x0b[4], x1a[4], x1b[4];
#pragma unroll
  for (int s = 0; s < 4; ++s) {
    const int off = s * 32;
    fa[s] = *(const float4*)(ap + off);
    fb[s] = *(const float4*)(ap + off + 4);
    x0a[s] = *(const float4*)(xp0 + off);
    x0b[s] = *(const float4*)(xp0 + off + 4);
    x1a[s] = *(const float4*)(xp1 + off);
    x1b[s] = *(const float4*)(xp1 + off + 4);
  }

  f32x4 acc0 = {0.f, 0.f, 0.f, 0.f}, acc1 = {0.f, 0.f, 0.f, 0.f};
#pragma unroll
  for (int s = 0; s < 4; ++s) {
    FragU Ah, Bh0, Bh1;
    pack8(fa[s], fb[s], Ah);
    pack8(x0a[s], x0b[s], Bh0);
    pack8(x1a[s], x1b[s], Bh1);
    acc0 = __builtin_amdgcn_mfma_f32_16x16x32_bf16(Ah.v, Bh0.v, acc0, 0, 0, 0);
    acc1 = __builtin_amdgcn_mfma_f32_16x16x32_bf16(Ah.v, Bh1.v, acc1, 0, 0, 0);
  }
  const int col = lane & 15, rq = (lane >> 4) * 4;
#pragma unroll
  for (int r = 0; r < 4; ++r) {
    red[wv][col * 16 + rq + r] = acc0[r];
    red[wv][(col + 16) * 16 + rq + r] = acc1[r];
  }
  __syncthreads();
  float* part = ws + (size_t)kq * PART_STRIDE + (size_t)m * 65536;
#pragma unroll
  for (int i = tid; i < 512; i += 256) {
    float s = (red[0][i] + red[1][i]) + (red[2][i] + red[3][i]);
    part[(size_t)(i >> 4) * D + lr + (i & 15)] = s;
  }
}

// ---------------- K0: bucketize q (pass 0) and k2 (pass 1) ----------------
__global__ __launch_bounds__(512) void k0_prep(float* __restrict__ ws,
                                               const float* __restrict__ bq,
                                               const float* __restrict__ bk) {
  __shared__ int cnt[64], off[65], cur[64];
  __shared__ float rmx[8], rmn[8];
  const int bx = blockIdx.x, t = threadIdx.x;
  const int b = bx & 31, pass = bx >> 5;
  const size_t qb = (size_t)b * D;
  float* meta = ws + META_OFF + b * 80;

  const size_t src = (pass ? 65536 : 0) + qb;
  float4 p0 = ((const float4*)(ws + src))[t];
  float4 p1 = ((const float4*)(ws + PART_STRIDE + src))[t];
  float4 p2 = ((const float4*)(ws + 2 * PART_STRIDE + src))[t];
  float4 p3 = ((const float4*)(ws + 3 * PART_STRIDE + src))[t];
  float4 bb = pass ? ((const float4*)bk)[t] : ((const float4*)bq)[t];
  float4 qv = {(p0.x + p1.x) + (p2.x + p3.x) + bb.x,
               (p0.y + p1.y) + (p2.y + p3.y) + bb.y,
               (p0.z + p1.z) + (p2.z + p3.z) + bb.z,
               (p0.w + p1.w) + (p2.w + p3.w) + bb.w};
  if (pass) { qv.x *= L2E; qv.y *= L2E; qv.z *= L2E; qv.w *= L2E; }
  float mx = fmaxf(fmaxf(qv.x, qv.y), fmaxf(qv.z, qv.w));
  float mn = fminf(fminf(qv.x, qv.y), fminf(qv.z, qv.w));
#pragma unroll
  for (int o = 32; o; o >>= 1) {
    mx = fmaxf(mx, __shfl_down(mx, o));
    mn = fminf(mn, __shfl_down(mn, o));
  }
  if ((t & 63) == 0) { rmx[t >> 6] = mx; rmn[t >> 6] = mn; }
  if (t < 64) cnt[t] = 0;
  __syncthreads();
  mx = rmx[0]; mn = rmn[0];
#pragma unroll
  for (int w = 1; w < 8; ++w) {
    mx = fmaxf(mx, rmx[w]);
    mn = fminf(mn, rmn[w]);
  }
  const float scale = (mx > mn) ? 64.0f / (mx - mn) : 0.f;
  float vals[4] = {qv.x, qv.y, qv.z, qv.w};
  int bi[4];
#pragma unroll
  for (int e = 0; e < 4; ++e) {
    bi[e] = (int)fminf(63.f, fmaxf(0.f, (vals[e] - mn) * scale));
    atomicAdd(&cnt[bi[e]], 1);
  }
  __syncthreads();
  if (t == 0) {
    int a = 0;
#pragma unroll
    for (int i = 0; i < 64; ++i) { off[i] = a; cur[i] = a; a += cnt[i]; }
    off[64] = a;
  }
  __syncthreads();
  const size_t vdst = (pass ? BK2_OFF : BQV_OFF) + qb;
  const size_t idst = (pass ? BKI_OFF : BQI_OFF) + qb;
#pragma unroll
  for (int e = 0; e < 4; ++e) {
    const int pos = atomicAdd(&cur[bi[e]], 1);
    ws[vdst + pos] = vals[e];
    ((int*)ws)[idst + pos] = t * 4 + e;
  }
  if (pass == 0) {
    if (t == 0) { meta[0] = mx; meta[1] = mn; meta[2] = scale; }
    if (t < 65) ((int*)meta)[8 + t] = off[t];
  }
}

// ---------------- K3: union-window Z, 4 groups/block (diagnostic) ----------
// grid 512 = 32 b x 16 gp; block does groups g = gp + 16*gi, gi in [0,4)
// (spread across sorted range -> balanced). qs staged ONCE (amortized 4x).
// Per group: R16-proven union-window Z + ballot partition + seg meta.
__global__ __launch_bounds__(512, 8) void k3_z(float* __restrict__ ws,
                                               const float* __restrict__ bv) {
  __shared__ float qs[2048];
  __shared__ float zs[512];
  __shared__ int ob[65];
  const int bx = blockIdx.x, t = threadIdx.x;
  const int b = bx & 31, gp = bx >> 5;       // gp in [0,16)
  const size_t qb = (size_t)b * D;
  const float* meta = ws + META_OFF + b * 80;

  ((float4*)qs)[t] = ((const float4*)(ws + BQV_OFF + qb))[t];
  if (t < 65) ob[t] = ((const int*)meta)[8 + t];
  const float qmx = meta[0], qmn = meta[1], scale = meta[2];
  const int jl = t & 31, ih = t >> 5;
  __syncthreads();

  for (int gi = 0; gi < 4; ++gi) {
    const int g = gp + 16 * gi;
    const int p = g * 32 + jl;               // bucketed (sorted) j position
    const float k2 = ws[BK2_OFF + qb + p];
    const int oj = ((const int*)ws)[BKI_OFF + qb + p];
    const float m2 = (k2 >= 0.f) ? k2 * qmx : k2 * qmn;
    const float nm2 = -m2;
    const float k2lo = __shfl(k2, 0);        // lanes = 32 sorted k2 (x2)
    const float k2hi = __shfl(k2, 31);

    int st, en;
    if (k2lo >= 0.f) {             // all-pos: union window = widest (k2lo)
      const float c = qmx - 40.f / k2lo;     // k2lo==0 -> -inf -> full
      const int B = (int)fminf(63.f, fmaxf(0.f, (c - qmn) * scale));
      st = ob[B] & ~3; en = 2048;
    } else if (k2hi < 0.f) {       // all-neg: union window = widest (k2hi)
      const float c = qmn + 40.f / (-k2hi);
      const int B = (int)fminf(63.f, fmaxf(0.f, (c - qmn) * scale));
      st = 0; en = (ob[B + 1] + 3) & ~3;
    } else {                       // mixed-sign: full window
      st = 0; en = 2048;
    }
    const int nq = (en - st) >> 2;
    const int i0 = st + (((nq * ih) >> 4) << 2);
    const int i1 = st + (((nq * (ih + 1)) >> 4) << 2);
    float z0 = 0.f, z1 = 0.f, z2 = 0.f, z3 = 0.f;
    for (int idx = i0; idx < i1; idx += 4) {
      float4 q4 = *(const float4*)&qs[idx];  // 2 addrs/wave -> broadcast
      z0 += fast_exp2(fmaf(q4.x, k2, nm2));
      z1 += fast_exp2(fmaf(q4.y, k2, nm2));
      z2 += fast_exp2(fmaf(q4.z, k2, nm2));
      z3 += fast_exp2(fmaf(q4.w, k2, nm2));
    }
    zs[ih * 32 + jl] = (z0 + z1) + (z2 + z3);
    __syncthreads();

    if (t < 32) {                            // wave 0, lanes 0-31 (jl==t)
      float Z = 0.f;
#pragma unroll
      for (int h = 0; h < 16; ++h) Z += zs[h * 32 + t];
      const float v = sum_parts(ws, 131072 + qb + oj) + bv[oj];
      const float d = __log2f(fabsf(v) / Z) - m2;  // v==0 -> -inf -> 2^ -> 0
      const unsigned long long msk = __ballot(v >= 0.f);
      const int npos = __popcll(msk);
      const int slot = (v >= 0.f) ? bits_below(msk)
                                  : 31 - bits_below(~msk & 0xFFFFFFFFull);
      float2* dst = (float2*)(ws + PKD_OFF) + ((size_t)b * 64 + g) * 32;
      dst[slot] = make_float2(k2, d);
      if (t == 0) ((int*)(ws + NPT_OFF))[b * 64 + g] = npos;
      float kmn = k2, kmx = k2, dmx = d;     // seg meta over 32 lanes
#pragma unroll
      for (int o = 16; o; o >>= 1) {
        kmn = fminf(kmn, __shfl_down(kmn, o, 32));
        kmx = fmaxf(kmx, __shfl_down(kmx, o, 32));
        dmx = fmaxf(dmx, __shfl_down(dmx, o, 32));
      }
      if (t == 0)
        ((float4*)(ws + SMETA_OFF))[b * 64 + g] =
            make_float4(kmn, kmx, dmx, 0.f);
    }
    __syncthreads();                         // zs reused next group
  }
}

// ---------------- K4: out over segs, 4 ic/block (diagnostic) ---------------
// grid 256 = 32 b x 8 icp; block does ic = icp + 8*ci, ci in [0,4). Stages
// the whole per-batch stream (16KB) ONCE (amortized 4x). Per ic: R16-proven
// wave-uniform seg loops with __all skip, scatter to orig i.
__global__ __launch_bounds__(512, 8) void k4_out(const float* __restrict__ ws,
                                                 float* __restrict__ out) {
  __shared__ float2 kd[2048];
  __shared__ float4 sm[64];
  __shared__ int np[64];
  __shared__ float rs[64 * 9];
  const int bx = blockIdx.x, t = threadIdx.x;
  const int b = bx & 31, icp = bx >> 5;      // icp in [0,8)
  const size_t qb = (size_t)b * D;

  const float4* src = (const float4*)((const float2*)(ws + PKD_OFF) +
                                      (size_t)b * 2048);
  ((float4*)kd)[t] = src[t];
  ((float4*)kd)[t + 512] = src[t + 512];
  if (t < 64) {
    np[t] = ((const int*)(ws + NPT_OFF))[b * 64 + t];
    sm[t] = ((const float4*)(ws + SMETA_OFF))[b * 64 + t];
  }
  const int il = t & 63, jh = t >> 6;
  __syncthreads();

  for (int ci = 0; ci < 4; ++ci) {
    const int ic = icp + 8 * ci;
    const int pos = ic * 64 + il;            // bucketed (sorted) q position
    const float qi = ws[BQV_OFF + qb + pos];
    const int oi = ((const int*)ws)[BQI_OFF + qb + pos];

    float p0 = 0.f, p1 = 0.f, p2 = 0.f, p3 = 0.f;
    float n0 = 0.f, n1 = 0.f, n2 = 0.f, n3 = 0.f;
#pragma unroll
    for (int s8 = 0; s8 < 8; ++s8) {
      const int sg = jh * 8 + s8;
      const float4 m = sm[sg];
      const float ub = fmaxf(m.x * qi, m.y * qi) + m.z;
      if (__all(ub < -28.f)) continue;       // whole wave skips the seg
      const float4* seg = (const float4*)(kd + sg * 32);
      const int npos = np[sg], gb = npos >> 2;
      for (int gq = 0; gq < gb; ++gq) {      // all-pos quads
        float4 a = seg[gq * 2], c = seg[gq * 2 + 1];
        p0 += fast_exp2(fmaf(qi, a.x, a.y));
        p1 += fast_exp2(fmaf(qi, a.z, a.w));
        p2 += fast_exp2(fmaf(qi, c.x, c.y));
        p3 += fast_exp2(fmaf(qi, c.z, c.w));
      }
      if (gb < 8) {
        {                                    // boundary quad: selects
          float4 a = seg[gb * 2], c = seg[gb * 2 + 1];
          const int base = gb * 4;
          float e0 = fast_exp2(fmaf(qi, a.x, a.y));
          float e1 = fast_exp2(fmaf(qi, a.z, a.w));
          float e2 = fast_exp2(fmaf(qi, c.x, c.y));
          float e3 = fast_exp2(fmaf(qi, c.z, c.w));
          if (base + 0 < npos) p0 += e0; else n0 += e0;
          if (base + 1 < npos) p1 += e1; else n1 += e1;
          if (base + 2 < npos) p2 += e2; else n2 += e2;
          if (base + 3 < npos) p3 += e3; else n3 += e3;
        }
        for (int gq = gb + 1; gq < 8; ++gq) {  // all-neg quads
          float4 a = seg[gq * 2], c = seg[gq * 2 + 1];
          n0 += fast_exp2(fmaf(qi, a.x, a.y));
          n1 += fast_exp2(fmaf(qi, a.z, a.w));
          n2 += fast_exp2(fmaf(qi, c.x, c.y));
          n3 += fast_exp2(fmaf(qi, c.z, c.w));
        }
      }
    }
    rs[il * 9 + jh] = ((p0 + p1) + (p2 + p3)) - ((n0 + n1) + (n2 + n3));
    __syncthreads();
    if (t < 64) {
      float sum = 0.f;
#pragma unroll
      for (int h = 0; h < 8; ++h) sum += rs[t * 9 + h];
      out[qb + oi] = sum;                    // t<64 -> il==t, own oi
    }
    __syncthreads();                         // rs reused next ic
  }
}

extern "C" void kernel_launch(void* const* d_in, const int* in_sizes, int n_in,
                              void* d_out, int out_size, void* d_ws, size_t ws_size,
                              hipStream_t stream) {
  (void)in_sizes; (void)n_in; (void)out_size; (void)ws_size;
  const float* x  = (const float*)d_in[0];
  const float* Wq = (const float*)d_in[1];
  const float* bq = (const float*)d_in[2];
  const float* Wk = (const float*)d_in[3];
  const float* bk = (const float*)d_in[4];
  const float* Wv = (const float*)d_in[5];
  const float* bv = (const float*)d_in[6];
  float* ws  = (float*)d_ws;
  float* out = (float*)d_out;

  k1_proj<<<1536, 256, 0, stream>>>(x, Wq, Wk, Wv, ws);
  k0_prep<<<64, 512, 0, stream>>>(ws, bq, bk);
  k3_z<<<512, 512, 0, stream>>>(ws, bv);
  k4_out<<<256, 512, 0, stream>>>(ws, out);
}